// Round 2
// baseline (2057.377 us; speedup 1.0000x reference)
//
#include <hip/hip_runtime.h>
#include <hip/hip_bf16.h>
#include <math.h>

#define EPSV 1e-5f

// ---------------- CSR build ----------------
// NOTE: harness delivers integer inputs as int32 (NOT int64, despite jnp.int64
// in the reference). Reading as long long caused the R1 memory-fault abort.

__global__ __launch_bounds__(256) void zero_int_kernel(int* __restrict__ p, int n) {
    int i = blockIdx.x * 256 + threadIdx.x;
    if (i < n) p[i] = 0;
}

__global__ __launch_bounds__(256) void count_kernel(const int* __restrict__ ei,
                                                    int* __restrict__ cnt, int E) {
    int e = blockIdx.x * 256 + threadIdx.x;
    if (e < E) {
        int d = ei[E + e];
        atomicAdd(&cnt[d], 1);
    }
}

__global__ __launch_bounds__(256) void scan1_kernel(const int* __restrict__ cnt,
                                                    int* __restrict__ partials, int n) {
    __shared__ int sdata[256];
    int t = threadIdx.x;
    int base = blockIdx.x * 1024 + t * 4;
    int s = 0;
#pragma unroll
    for (int j = 0; j < 4; ++j) { int i = base + j; if (i < n) s += cnt[i]; }
    sdata[t] = s;
    __syncthreads();
    for (int off = 128; off > 0; off >>= 1) {
        if (t < off) sdata[t] += sdata[t + off];
        __syncthreads();
    }
    if (t == 0) partials[blockIdx.x] = sdata[0];
}

__global__ void scan2_kernel(int* __restrict__ partials, int nb) {
    if (threadIdx.x == 0 && blockIdx.x == 0) {
        int acc = 0;
        for (int i = 0; i < nb; ++i) { int v = partials[i]; partials[i] = acc; acc += v; }
    }
}

__global__ __launch_bounds__(256) void scan3_kernel(const int* __restrict__ cnt,
                                                    const int* __restrict__ partials,
                                                    int* __restrict__ rowptr,
                                                    int* __restrict__ cursor,
                                                    float* __restrict__ dinv,
                                                    float* __restrict__ selfnorm,
                                                    int n, int E) {
    __shared__ int sdata[256];
    int t = threadIdx.x;
    int base = blockIdx.x * 1024 + t * 4;
    int loc[4];
    int s = 0;
#pragma unroll
    for (int j = 0; j < 4; ++j) {
        int i = base + j;
        loc[j] = (i < n) ? cnt[i] : 0;
        s += loc[j];
    }
    sdata[t] = s;
    __syncthreads();
    if (t == 0) {
        int a = 0;
        for (int i = 0; i < 256; ++i) { int v = sdata[i]; sdata[i] = a; a += v; }
    }
    __syncthreads();
    int run = partials[blockIdx.x] + sdata[t];
#pragma unroll
    for (int j = 0; j < 4; ++j) {
        int i = base + j;
        if (i < n) {
            rowptr[i] = run;
            cursor[i] = run;
            float df = (float)(loc[j] + 1);   // deg = indeg + self-loop
            dinv[i] = rsqrtf(df);
            selfnorm[i] = 1.0f / df;
            run += loc[j];
        }
    }
    if (blockIdx.x == 0 && t == 0) rowptr[n] = E;
}

__global__ __launch_bounds__(256) void scatter_kernel(const int* __restrict__ ei,
                                                      int* __restrict__ cursor,
                                                      int* __restrict__ csr, int E) {
    int e = blockIdx.x * 256 + threadIdx.x;
    if (e < E) {
        int s = ei[e];
        int d = ei[E + e];
        int pos = atomicAdd(&cursor[d], 1);
        csr[pos] = s;
    }
}

// ---------------- fp32 tiled GEMM: C[n,M] = A[n,K] @ W[K,M] ----------------
// 64x64 block tile, BK=16, 256 threads, 4x4 micro-tile per thread.

#define LSTR 68  // LDS row stride (floats): 64 + 4 keeps float4 alignment, breaks bank aliasing

__global__ __launch_bounds__(256) void gemm_kernel(const float* __restrict__ A,
                                                   const float* __restrict__ W,
                                                   float* __restrict__ C,
                                                   int nrows, int K, int M) {
    __shared__ float As[16 * LSTR];  // [k][row]
    __shared__ float Ws[16 * LSTR];  // [k][col]
    int tid = threadIdx.x;
    int tx = tid & 15, ty = tid >> 4;
    int row0 = blockIdx.x * 64, col0 = blockIdx.y * 64;

    int arow = tid >> 2, akg = tid & 3;
    int grow = row0 + arow;
    bool avalid = grow < nrows;
    const float* aptr = A + (size_t)grow * K + akg * 4;

    float acc[4][4] = {{0.f}};

    for (int k0 = 0; k0 < K; k0 += 16) {
        float4 av = make_float4(0.f, 0.f, 0.f, 0.f);
        if (avalid) av = *(const float4*)(aptr + k0);
        As[(akg * 4 + 0) * LSTR + arow] = av.x;
        As[(akg * 4 + 1) * LSTR + arow] = av.y;
        As[(akg * 4 + 2) * LSTR + arow] = av.z;
        As[(akg * 4 + 3) * LSTR + arow] = av.w;

        int gc = col0 + tx * 4;
        const float* wrow = W + (size_t)(k0 + ty) * M;
        float4 wv;
        if (gc + 3 < M) {
            wv = *(const float4*)(wrow + gc);
        } else {
            wv.x = (gc + 0 < M) ? wrow[gc + 0] : 0.f;
            wv.y = (gc + 1 < M) ? wrow[gc + 1] : 0.f;
            wv.z = (gc + 2 < M) ? wrow[gc + 2] : 0.f;
            wv.w = (gc + 3 < M) ? wrow[gc + 3] : 0.f;
        }
        *(float4*)(&Ws[ty * LSTR + tx * 4]) = wv;
        __syncthreads();

#pragma unroll
        for (int kk = 0; kk < 16; ++kk) {
            float4 a = *(const float4*)(&As[kk * LSTR + ty * 4]);
            float4 b = *(const float4*)(&Ws[kk * LSTR + tx * 4]);
            acc[0][0] += a.x * b.x; acc[0][1] += a.x * b.y; acc[0][2] += a.x * b.z; acc[0][3] += a.x * b.w;
            acc[1][0] += a.y * b.x; acc[1][1] += a.y * b.y; acc[1][2] += a.y * b.z; acc[1][3] += a.y * b.w;
            acc[2][0] += a.z * b.x; acc[2][1] += a.z * b.y; acc[2][2] += a.z * b.z; acc[2][3] += a.z * b.w;
            acc[3][0] += a.w * b.x; acc[3][1] += a.w * b.y; acc[3][2] += a.w * b.z; acc[3][3] += a.w * b.w;
        }
        __syncthreads();
    }

    int c0 = col0 + tx * 4;
#pragma unroll
    for (int i = 0; i < 4; ++i) {
        int r = row0 + ty * 4 + i;
        if (r >= nrows) continue;
        if (c0 + 3 < M) {
            *(float4*)(C + (size_t)r * M + c0) =
                make_float4(acc[i][0], acc[i][1], acc[i][2], acc[i][3]);
        } else {
#pragma unroll
            for (int j = 0; j < 4; ++j)
                if (c0 + j < M) C[(size_t)r * M + c0 + j] = acc[i][j];
        }
    }
}

// ---------------- fused aggregate + self + bias + BN + ReLU (256-wide) ----------------
// One wave per node; lane l owns features [4l, 4l+4).

__global__ __launch_bounds__(256) void agg_bn_relu_kernel(const float* __restrict__ h,
                                                          const int* __restrict__ rowptr,
                                                          const int* __restrict__ csr,
                                                          const float* __restrict__ dinv,
                                                          const float* __restrict__ selfnorm,
                                                          const float* __restrict__ b,
                                                          const float* __restrict__ g,
                                                          const float* __restrict__ beta,
                                                          const float* __restrict__ m,
                                                          const float* __restrict__ v,
                                                          float* __restrict__ y, int n) {
    int wave = (blockIdx.x * 256 + threadIdx.x) >> 6;
    int lane = threadIdx.x & 63;
    if (wave >= n) return;
    int node = wave;
    int beg = rowptr[node], end = rowptr[node + 1];

    float4 acc = make_float4(0.f, 0.f, 0.f, 0.f);
    for (int k = beg; k < end; ++k) {
        int s = csr[k];
        float w = dinv[s];
        float4 hv = *(const float4*)(h + (size_t)s * 256 + lane * 4);
        acc.x += w * hv.x; acc.y += w * hv.y; acc.z += w * hv.z; acc.w += w * hv.w;
    }
    float di = dinv[node];
    float sn = selfnorm[node];
    float4 hd = *(const float4*)(h + (size_t)node * 256 + lane * 4);
    float4 bb = *(const float4*)(b + lane * 4);
    float4 gg = *(const float4*)(g + lane * 4);
    float4 bt = *(const float4*)(beta + lane * 4);
    float4 mm = *(const float4*)(m + lane * 4);
    float4 vv = *(const float4*)(v + lane * 4);

    float4 out;
    {
        float val = acc.x * di + hd.x * sn + bb.x;
        float sc = gg.x * rsqrtf(vv.x + EPSV);
        out.x = fmaxf((val - mm.x) * sc + bt.x, 0.f);
    }
    {
        float val = acc.y * di + hd.y * sn + bb.y;
        float sc = gg.y * rsqrtf(vv.y + EPSV);
        out.y = fmaxf((val - mm.y) * sc + bt.y, 0.f);
    }
    {
        float val = acc.z * di + hd.z * sn + bb.z;
        float sc = gg.z * rsqrtf(vv.z + EPSV);
        out.z = fmaxf((val - mm.z) * sc + bt.z, 0.f);
    }
    {
        float val = acc.w * di + hd.w * sn + bb.w;
        float sc = gg.w * rsqrtf(vv.w + EPSV);
        out.w = fmaxf((val - mm.w) * sc + bt.w, 0.f);
    }
    *(float4*)(y + (size_t)node * 256 + lane * 4) = out;
}

// ---------------- layer-3 aggregate + bias + log_softmax (40-wide) ----------------
// One wave per node; lanes 0..39 each own one feature.

__global__ __launch_bounds__(256) void agg3_lsm_kernel(const float* __restrict__ h,
                                                       const int* __restrict__ rowptr,
                                                       const int* __restrict__ csr,
                                                       const float* __restrict__ dinv,
                                                       const float* __restrict__ selfnorm,
                                                       const float* __restrict__ b,
                                                       float* __restrict__ out, int n) {
    int wave = (blockIdx.x * 256 + threadIdx.x) >> 6;
    int lane = threadIdx.x & 63;
    if (wave >= n) return;
    int node = wave;
    bool act = lane < 40;
    int beg = rowptr[node], end = rowptr[node + 1];

    float acc = 0.f;
    for (int k = beg; k < end; ++k) {
        int s = csr[k];
        float w = dinv[s];
        float hv = act ? h[(size_t)s * 40 + lane] : 0.f;
        acc += w * hv;
    }
    float z;
    if (act) {
        z = acc * dinv[node] + h[(size_t)node * 40 + lane] * selfnorm[node] + b[lane];
    } else {
        z = -INFINITY;
    }
    float mx = z;
#pragma unroll
    for (int off = 32; off > 0; off >>= 1) mx = fmaxf(mx, __shfl_xor(mx, off, 64));
    float e = act ? expf(z - mx) : 0.f;
    float se = e;
#pragma unroll
    for (int off = 32; off > 0; off >>= 1) se += __shfl_xor(se, off, 64);
    float ls = z - mx - logf(se);
    if (act) out[(size_t)node * 40 + lane] = ls;
}

// ---------------- launcher ----------------

extern "C" void kernel_launch(void* const* d_in, const int* in_sizes, int n_in,
                              void* d_out, int out_size, void* d_ws, size_t ws_size,
                              hipStream_t stream) {
    const float* x   = (const float*)d_in[0];
    const int* ei    = (const int*)d_in[1];   // int32! (harness converts integer inputs)
    const float* W1 = (const float*)d_in[2];
    const float* b1 = (const float*)d_in[3];
    const float* g1 = (const float*)d_in[4];
    const float* be1 = (const float*)d_in[5];
    const float* m1 = (const float*)d_in[6];
    const float* v1 = (const float*)d_in[7];
    const float* W2 = (const float*)d_in[8];
    const float* b2 = (const float*)d_in[9];
    const float* g2 = (const float*)d_in[10];
    const float* be2 = (const float*)d_in[11];
    const float* m2 = (const float*)d_in[12];
    const float* v2 = (const float*)d_in[13];
    const float* W3 = (const float*)d_in[14];
    const float* b3 = (const float*)d_in[15];

    const int N = in_sizes[0] / 128;
    const int E = in_sizes[1] / 2;

    float* out_lsm = (float*)d_out;                    // [N,40]
    float* out_emb = (float*)d_out + (size_t)N * 40;   // [N,256]

    char* ws = (char*)d_ws;
    size_t off = 0;
    auto carve = [&](size_t bytes) -> void* {
        void* p = ws + off;
        off = (off + bytes + 255) & ~(size_t)255;
        return p;
    };
    int* cnt      = (int*)carve((size_t)N * 4);
    int* rowptr   = (int*)carve((size_t)(N + 1) * 4);
    int* cursor   = (int*)carve((size_t)N * 4);
    int* partials = (int*)carve(1024);
    int* csr      = (int*)carve((size_t)E * 4);
    float* dinv     = (float*)carve((size_t)N * 4);
    float* selfnorm = (float*)carve((size_t)N * 4);
    float* hbuf = (float*)carve((size_t)N * 256 * 4);
    float* ybuf = (float*)carve((size_t)N * 256 * 4);
    float* h3   = (float*)carve((size_t)N * 40 * 4);
    (void)ws_size; (void)n_in; (void)out_size;

    int nb1k = (N + 1023) / 1024;
    dim3 blk(256);

    hipLaunchKernelGGL(zero_int_kernel, dim3((N + 255) / 256), blk, 0, stream, cnt, N);
    hipLaunchKernelGGL(count_kernel, dim3((E + 255) / 256), blk, 0, stream, ei, cnt, E);
    hipLaunchKernelGGL(scan1_kernel, dim3(nb1k), blk, 0, stream, cnt, partials, N);
    hipLaunchKernelGGL(scan2_kernel, dim3(1), dim3(64), 0, stream, partials, nb1k);
    hipLaunchKernelGGL(scan3_kernel, dim3(nb1k), blk, 0, stream, cnt, partials, rowptr, cursor,
                       dinv, selfnorm, N, E);
    hipLaunchKernelGGL(scatter_kernel, dim3((E + 255) / 256), blk, 0, stream, ei, cursor, csr, E);

    dim3 ggrid((N + 63) / 64, 4);
    dim3 agrid((N + 3) / 4);

    // layer 1
    hipLaunchKernelGGL(gemm_kernel, ggrid, blk, 0, stream, x, W1, hbuf, N, 128, 256);
    hipLaunchKernelGGL(agg_bn_relu_kernel, agrid, blk, 0, stream, hbuf, rowptr, csr, dinv,
                       selfnorm, b1, g1, be1, m1, v1, ybuf, N);
    // layer 2
    hipLaunchKernelGGL(gemm_kernel, ggrid, blk, 0, stream, ybuf, W2, hbuf, N, 256, 256);
    hipLaunchKernelGGL(agg_bn_relu_kernel, agrid, blk, 0, stream, hbuf, rowptr, csr, dinv,
                       selfnorm, b2, g2, be2, m2, v2, out_emb, N);
    // layer 3
    dim3 ggrid3((N + 63) / 64, 1);
    hipLaunchKernelGGL(gemm_kernel, ggrid3, blk, 0, stream, out_emb, W3, h3, N, 256, 40);
    hipLaunchKernelGGL(agg3_lsm_kernel, agrid, blk, 0, stream, h3, rowptr, csr, dinv, selfnorm,
                       b3, out_lsm, N);
}

// Round 3
// 1385.354 us; speedup vs baseline: 1.4851x; 1.4851x over previous
//
#include <hip/hip_runtime.h>
#include <math.h>

#define EPSV 1e-5f

typedef __attribute__((ext_vector_type(8))) short bf16x8;
typedef __attribute__((ext_vector_type(4))) float floatx4;

__device__ __forceinline__ unsigned short f32_to_bf16(float f) {
    unsigned int u = __float_as_uint(f);
    unsigned int r = (u + 0x7fffu + ((u >> 16) & 1u)) >> 16;  // RNE
    return (unsigned short)r;
}

__device__ __forceinline__ float bf16_lo(unsigned int u) { return __uint_as_float(u << 16); }
__device__ __forceinline__ float bf16_hi(unsigned int u) { return __uint_as_float(u & 0xffff0000u); }

// ---------------- CSR build (int32 edge_index — harness converts ints to int32) ----------------

__global__ __launch_bounds__(256) void zero_int_kernel(int* __restrict__ p, int n) {
    int i = blockIdx.x * 256 + threadIdx.x;
    if (i < n) p[i] = 0;
}

__global__ __launch_bounds__(256) void count_kernel(const int* __restrict__ ei,
                                                    int* __restrict__ cnt, int E) {
    int e = blockIdx.x * 256 + threadIdx.x;
    if (e < E) atomicAdd(&cnt[ei[E + e]], 1);
}

__global__ __launch_bounds__(256) void scan1_kernel(const int* __restrict__ cnt,
                                                    int* __restrict__ partials, int n) {
    __shared__ int sdata[256];
    int t = threadIdx.x;
    int base = blockIdx.x * 1024 + t * 4;
    int s = 0;
#pragma unroll
    for (int j = 0; j < 4; ++j) { int i = base + j; if (i < n) s += cnt[i]; }
    sdata[t] = s;
    __syncthreads();
    for (int off = 128; off > 0; off >>= 1) {
        if (t < off) sdata[t] += sdata[t + off];
        __syncthreads();
    }
    if (t == 0) partials[blockIdx.x] = sdata[0];
}

__global__ void scan2_kernel(int* __restrict__ partials, int nb) {
    if (threadIdx.x == 0 && blockIdx.x == 0) {
        int acc = 0;
        for (int i = 0; i < nb; ++i) { int v = partials[i]; partials[i] = acc; acc += v; }
    }
}

__global__ __launch_bounds__(256) void scan3_kernel(const int* __restrict__ cnt,
                                                    const int* __restrict__ partials,
                                                    int* __restrict__ rowptr,
                                                    int* __restrict__ cursor,
                                                    float* __restrict__ dinv,
                                                    float* __restrict__ selfnorm,
                                                    int n, int E) {
    __shared__ int sdata[256];
    int t = threadIdx.x;
    int base = blockIdx.x * 1024 + t * 4;
    int loc[4];
    int s = 0;
#pragma unroll
    for (int j = 0; j < 4; ++j) {
        int i = base + j;
        loc[j] = (i < n) ? cnt[i] : 0;
        s += loc[j];
    }
    sdata[t] = s;
    __syncthreads();
    if (t == 0) {
        int a = 0;
        for (int i = 0; i < 256; ++i) { int v = sdata[i]; sdata[i] = a; a += v; }
    }
    __syncthreads();
    int run = partials[blockIdx.x] + sdata[t];
#pragma unroll
    for (int j = 0; j < 4; ++j) {
        int i = base + j;
        if (i < n) {
            rowptr[i] = run;
            cursor[i] = run;
            float df = (float)(loc[j] + 1);
            dinv[i] = rsqrtf(df);
            selfnorm[i] = 1.0f / df;
            run += loc[j];
        }
    }
    if (blockIdx.x == 0 && t == 0) rowptr[n] = E;
}

__global__ __launch_bounds__(256) void scatter_kernel(const int* __restrict__ ei,
                                                      int* __restrict__ cursor,
                                                      int* __restrict__ csr, int E) {
    int e = blockIdx.x * 256 + threadIdx.x;
    if (e < E) {
        int pos = atomicAdd(&cursor[ei[E + e]], 1);
        csr[pos] = ei[e];
    }
}

// ---------------- casts ----------------

__global__ __launch_bounds__(256) void cast_bf16_kernel(const float* __restrict__ in,
                                                        unsigned short* __restrict__ out, int n4) {
    int i = blockIdx.x * 256 + threadIdx.x;
    if (i < n4) {
        float4 f = ((const float4*)in)[i];
        ushort4 o;
        o.x = f32_to_bf16(f.x); o.y = f32_to_bf16(f.y);
        o.z = f32_to_bf16(f.z); o.w = f32_to_bf16(f.w);
        ((ushort4*)out)[i] = o;
    }
}

// W[K x M] fp32 -> Wt[M x K] bf16
__global__ __launch_bounds__(256) void cast_transpose_kernel(const float* __restrict__ in,
                                                             unsigned short* __restrict__ out,
                                                             int K, int M) {
    int i = blockIdx.x * 256 + threadIdx.x;
    if (i < K * M) {
        int k = i / M, m2 = i - k * M;
        out[(size_t)m2 * K + k] = f32_to_bf16(in[i]);
    }
}

// ---------------- bf16 MFMA GEMM: C[n,M] = A[n,K] @ W[K,M], Wt is [M,K] ----------------
// 64x64 block tile, 4 waves in 2x2, each wave 32x32 (2x2 mfma_f32_16x16x32_bf16 tiles).
// LDS stride 40 shorts (80 B): 16B-aligned b128 frag reads, ~2-way (free) bank aliasing.

__global__ __launch_bounds__(256) void gemm_bf16_kernel(const unsigned short* __restrict__ A,
                                                        const unsigned short* __restrict__ Wt,
                                                        unsigned short* __restrict__ Cb,
                                                        float* __restrict__ Cf,
                                                        int nrows, int K, int M) {
    __shared__ short As[64 * 40];
    __shared__ short Bs[64 * 40];
    int tid = threadIdx.x;
    int wave = tid >> 6, lane = tid & 63;
    int quad = lane >> 4, l16 = lane & 15;
    int wr = (wave >> 1) * 32, wc = (wave & 1) * 32;
    int row0 = blockIdx.x * 64, col0 = blockIdx.y * 64;

    int srow = tid >> 2, sseg = tid & 3;  // staging: 64 rows x 4 segments of 8 bf16

    floatx4 acc[2][2];
#pragma unroll
    for (int i = 0; i < 2; ++i)
#pragma unroll
        for (int j = 0; j < 2; ++j)
#pragma unroll
            for (int r = 0; r < 4; ++r) acc[i][j][r] = 0.f;

    for (int k0 = 0; k0 < K; k0 += 32) {
        uint4 av = make_uint4(0, 0, 0, 0);
        int gr = row0 + srow;
        if (gr < nrows) av = *(const uint4*)(A + (size_t)gr * K + k0 + sseg * 8);
        uint4 bv = make_uint4(0, 0, 0, 0);
        int gc = col0 + srow;
        if (gc < M) bv = *(const uint4*)(Wt + (size_t)gc * K + k0 + sseg * 8);

        *(uint4*)(As + srow * 40 + sseg * 8) = av;
        *(uint4*)(Bs + srow * 40 + sseg * 8) = bv;
        __syncthreads();

        bf16x8 af[2], bf[2];
#pragma unroll
        for (int i = 0; i < 2; ++i)
            af[i] = *(const bf16x8*)(As + (wr + i * 16 + l16) * 40 + quad * 8);
#pragma unroll
        for (int j = 0; j < 2; ++j)
            bf[j] = *(const bf16x8*)(Bs + (wc + j * 16 + l16) * 40 + quad * 8);

#pragma unroll
        for (int i = 0; i < 2; ++i)
#pragma unroll
            for (int j = 0; j < 2; ++j)
                acc[i][j] = __builtin_amdgcn_mfma_f32_16x16x32_bf16(af[i], bf[j], acc[i][j], 0, 0, 0);
        __syncthreads();  // protect next iteration's staging stores
    }

    // C/D layout: col = lane&15, row = (lane>>4)*4 + reg
#pragma unroll
    for (int i = 0; i < 2; ++i) {
#pragma unroll
        for (int r = 0; r < 4; ++r) {
            int row = row0 + wr + i * 16 + quad * 4 + r;
            if (row >= nrows) continue;
#pragma unroll
            for (int j = 0; j < 2; ++j) {
                int col = col0 + wc + j * 16 + l16;
                if (col < M) {
                    float vv = acc[i][j][r];
                    if (Cb) Cb[(size_t)row * M + col] = f32_to_bf16(vv);
                    if (Cf) Cf[(size_t)row * M + col] = vv;
                }
            }
        }
    }
}

// ---------------- fused bf16 aggregate + self + bias + BN + ReLU (256 feats) ----------------
// Half-wave (32 lanes) per node; lane owns 8 feats (16 B bf16). fp32 accumulate.

__global__ __launch_bounds__(256) void agg_bn_relu_bf16_kernel(
    const unsigned short* __restrict__ h,
    const int* __restrict__ rowptr, const int* __restrict__ csr,
    const float* __restrict__ dinv, const float* __restrict__ selfnorm,
    const float* __restrict__ b, const float* __restrict__ g,
    const float* __restrict__ beta, const float* __restrict__ m,
    const float* __restrict__ v,
    unsigned short* __restrict__ ybf, float* __restrict__ yfp, int n) {
    int gtid = blockIdx.x * 256 + threadIdx.x;
    int lane = threadIdx.x & 63;
    int half = lane >> 5, sub = lane & 31;
    int node = (gtid >> 6) * 2 + half;
    if (node >= n) return;
    int beg = rowptr[node], end = rowptr[node + 1];
    int fb = sub * 8;

    float acc[8] = {0.f, 0.f, 0.f, 0.f, 0.f, 0.f, 0.f, 0.f};
    for (int e = beg; e < end; ++e) {
        int s = csr[e];
        float w = dinv[s];
        uint4 u = *(const uint4*)(h + (size_t)s * 256 + fb);
        acc[0] += w * bf16_lo(u.x); acc[1] += w * bf16_hi(u.x);
        acc[2] += w * bf16_lo(u.y); acc[3] += w * bf16_hi(u.y);
        acc[4] += w * bf16_lo(u.z); acc[5] += w * bf16_hi(u.z);
        acc[6] += w * bf16_lo(u.w); acc[7] += w * bf16_hi(u.w);
    }
    float di = dinv[node], sn = selfnorm[node];
    uint4 us = *(const uint4*)(h + (size_t)node * 256 + fb);
    float hs[8];
    hs[0] = bf16_lo(us.x); hs[1] = bf16_hi(us.x);
    hs[2] = bf16_lo(us.y); hs[3] = bf16_hi(us.y);
    hs[4] = bf16_lo(us.z); hs[5] = bf16_hi(us.z);
    hs[6] = bf16_lo(us.w); hs[7] = bf16_hi(us.w);

    float outv[8];
#pragma unroll
    for (int j = 0; j < 8; ++j) {
        float val = acc[j] * di + hs[j] * sn + b[fb + j];
        float sc = g[fb + j] * rsqrtf(v[fb + j] + EPSV);
        outv[j] = fmaxf((val - m[fb + j]) * sc + beta[fb + j], 0.f);
    }
    if (ybf) {
        uint4 o;
        o.x = ((unsigned int)f32_to_bf16(outv[1]) << 16) | f32_to_bf16(outv[0]);
        o.y = ((unsigned int)f32_to_bf16(outv[3]) << 16) | f32_to_bf16(outv[2]);
        o.z = ((unsigned int)f32_to_bf16(outv[5]) << 16) | f32_to_bf16(outv[4]);
        o.w = ((unsigned int)f32_to_bf16(outv[7]) << 16) | f32_to_bf16(outv[6]);
        *(uint4*)(ybf + (size_t)node * 256 + fb) = o;
    }
    if (yfp) {
        *(float4*)(yfp + (size_t)node * 256 + fb) = make_float4(outv[0], outv[1], outv[2], outv[3]);
        *(float4*)(yfp + (size_t)node * 256 + fb + 4) = make_float4(outv[4], outv[5], outv[6], outv[7]);
    }
}

// ---------------- layer-3 aggregate + bias + log_softmax (40-wide) ----------------

__global__ __launch_bounds__(256) void agg3_lsm_kernel(const float* __restrict__ h,
                                                       const int* __restrict__ rowptr,
                                                       const int* __restrict__ csr,
                                                       const float* __restrict__ dinv,
                                                       const float* __restrict__ selfnorm,
                                                       const float* __restrict__ b,
                                                       float* __restrict__ out, int n) {
    int wave = (blockIdx.x * 256 + threadIdx.x) >> 6;
    int lane = threadIdx.x & 63;
    if (wave >= n) return;
    int node = wave;
    bool act = lane < 40;
    int beg = rowptr[node], end = rowptr[node + 1];

    float acc = 0.f;
    for (int k = beg; k < end; ++k) {
        int s = csr[k];
        float w = dinv[s];
        float hv = act ? h[(size_t)s * 40 + lane] : 0.f;
        acc += w * hv;
    }
    float z;
    if (act) {
        z = acc * dinv[node] + h[(size_t)node * 40 + lane] * selfnorm[node] + b[lane];
    } else {
        z = -INFINITY;
    }
    float mx = z;
#pragma unroll
    for (int off = 32; off > 0; off >>= 1) mx = fmaxf(mx, __shfl_xor(mx, off, 64));
    float e = act ? expf(z - mx) : 0.f;
    float se = e;
#pragma unroll
    for (int off = 32; off > 0; off >>= 1) se += __shfl_xor(se, off, 64);
    float ls = z - mx - logf(se);
    if (act) out[(size_t)node * 40 + lane] = ls;
}

// ---------------- launcher ----------------

extern "C" void kernel_launch(void* const* d_in, const int* in_sizes, int n_in,
                              void* d_out, int out_size, void* d_ws, size_t ws_size,
                              hipStream_t stream) {
    const float* x  = (const float*)d_in[0];
    const int* ei   = (const int*)d_in[1];   // int32
    const float* W1 = (const float*)d_in[2];
    const float* b1 = (const float*)d_in[3];
    const float* g1 = (const float*)d_in[4];
    const float* be1 = (const float*)d_in[5];
    const float* m1 = (const float*)d_in[6];
    const float* v1 = (const float*)d_in[7];
    const float* W2 = (const float*)d_in[8];
    const float* b2 = (const float*)d_in[9];
    const float* g2 = (const float*)d_in[10];
    const float* be2 = (const float*)d_in[11];
    const float* m2 = (const float*)d_in[12];
    const float* v2 = (const float*)d_in[13];
    const float* W3 = (const float*)d_in[14];
    const float* b3 = (const float*)d_in[15];

    const int N = in_sizes[0] / 128;
    const int E = in_sizes[1] / 2;

    float* out_lsm = (float*)d_out;                    // [N,40]
    float* out_emb = (float*)d_out + (size_t)N * 40;   // [N,256]

    char* ws = (char*)d_ws;
    size_t off = 0;
    auto carve = [&](size_t bytes) -> void* {
        void* p = ws + off;
        off = (off + bytes + 255) & ~(size_t)255;
        return p;
    };
    int* cnt      = (int*)carve((size_t)N * 4);
    int* rowptr   = (int*)carve((size_t)(N + 1) * 4);
    int* cursor   = (int*)carve((size_t)N * 4);
    int* partials = (int*)carve(1024);
    int* csr      = (int*)carve((size_t)E * 4);
    float* dinv     = (float*)carve((size_t)N * 4);
    float* selfnorm = (float*)carve((size_t)N * 4);
    unsigned short* xbf  = (unsigned short*)carve((size_t)N * 128 * 2);
    unsigned short* W1t  = (unsigned short*)carve((size_t)256 * 128 * 2);
    unsigned short* W2t  = (unsigned short*)carve((size_t)256 * 256 * 2);
    unsigned short* W3t  = (unsigned short*)carve((size_t)40 * 256 * 2);
    unsigned short* hbf  = (unsigned short*)carve((size_t)N * 256 * 2);
    unsigned short* y1bf = (unsigned short*)carve((size_t)N * 256 * 2);
    unsigned short* y2bf = (unsigned short*)carve((size_t)N * 256 * 2);
    float* h3 = (float*)carve((size_t)N * 40 * 4);
    (void)ws_size; (void)n_in; (void)out_size;

    int nb1k = (N + 1023) / 1024;
    dim3 blk(256);

    // CSR + norms
    hipLaunchKernelGGL(zero_int_kernel, dim3((N + 255) / 256), blk, 0, stream, cnt, N);
    hipLaunchKernelGGL(count_kernel, dim3((E + 255) / 256), blk, 0, stream, ei, cnt, E);
    hipLaunchKernelGGL(scan1_kernel, dim3(nb1k), blk, 0, stream, cnt, partials, N);
    hipLaunchKernelGGL(scan2_kernel, dim3(1), dim3(64), 0, stream, partials, nb1k);
    hipLaunchKernelGGL(scan3_kernel, dim3(nb1k), blk, 0, stream, cnt, partials, rowptr, cursor,
                       dinv, selfnorm, N, E);
    hipLaunchKernelGGL(scatter_kernel, dim3((E + 255) / 256), blk, 0, stream, ei, cursor, csr, E);

    // casts
    int xn4 = N * 128 / 4;
    hipLaunchKernelGGL(cast_bf16_kernel, dim3((xn4 + 255) / 256), blk, 0, stream, x, xbf, xn4);
    hipLaunchKernelGGL(cast_transpose_kernel, dim3((128 * 256 + 255) / 256), blk, 0, stream,
                       W1, W1t, 128, 256);
    hipLaunchKernelGGL(cast_transpose_kernel, dim3((256 * 256 + 255) / 256), blk, 0, stream,
                       W2, W2t, 256, 256);
    hipLaunchKernelGGL(cast_transpose_kernel, dim3((256 * 40 + 255) / 256), blk, 0, stream,
                       W3, W3t, 256, 40);

    dim3 ggrid((N + 63) / 64, 4);
    dim3 ggrid3((N + 63) / 64, 1);
    dim3 agrid((N + 7) / 8);   // 8 nodes per 256-thread block (half-wave per node)
    dim3 agrid3((N + 3) / 4);  // wave per node

    // layer 1
    hipLaunchKernelGGL(gemm_bf16_kernel, ggrid, blk, 0, stream, xbf, W1t, hbf, (float*)nullptr,
                       N, 128, 256);
    hipLaunchKernelGGL(agg_bn_relu_bf16_kernel, agrid, blk, 0, stream, hbf, rowptr, csr, dinv,
                       selfnorm, b1, g1, be1, m1, v1, y1bf, (float*)nullptr, N);
    // layer 2
    hipLaunchKernelGGL(gemm_bf16_kernel, ggrid, blk, 0, stream, y1bf, W2t, hbf, (float*)nullptr,
                       N, 256, 256);
    hipLaunchKernelGGL(agg_bn_relu_bf16_kernel, agrid, blk, 0, stream, hbf, rowptr, csr, dinv,
                       selfnorm, b2, g2, be2, m2, v2, y2bf, out_emb, N);
    // layer 3
    hipLaunchKernelGGL(gemm_bf16_kernel, ggrid3, blk, 0, stream, y2bf, W3t,
                       (unsigned short*)nullptr, h3, N, 256, 40);
    hipLaunchKernelGGL(agg3_lsm_kernel, agrid3, blk, 0, stream, h3, rowptr, csr, dinv, selfnorm,
                       b3, out_lsm, N);
}

// Round 5
// 1200.504 us; speedup vs baseline: 1.7138x; 1.1540x over previous
//
#include <hip/hip_runtime.h>
#include <math.h>

#define EPSV 1e-5f

typedef __attribute__((ext_vector_type(8))) short bf16x8;
typedef __attribute__((ext_vector_type(4))) float floatx4;

__device__ __forceinline__ unsigned short f32_to_bf16(float f) {
    unsigned int u = __float_as_uint(f);
    unsigned int r = (u + 0x7fffu + ((u >> 16) & 1u)) >> 16;  // RNE
    return (unsigned short)r;
}
__device__ __forceinline__ float bf16_lo(unsigned int u) { return __uint_as_float(u << 16); }
__device__ __forceinline__ float bf16_hi(unsigned int u) { return __uint_as_float(u & 0xffff0000u); }

// ---------------- CSR build (edge_index arrives as int32) ----------------

__global__ __launch_bounds__(256) void zero_int_kernel(int* __restrict__ p, int n) {
    int i = blockIdx.x * 256 + threadIdx.x;
    if (i < n) p[i] = 0;
}

__global__ __launch_bounds__(256) void count_kernel(const int* __restrict__ ei,
                                                    int* __restrict__ cnt, int E) {
    int e = blockIdx.x * 256 + threadIdx.x;
    if (e < E) atomicAdd(&cnt[ei[E + e]], 1);
}

__global__ __launch_bounds__(256) void scan1_kernel(const int* __restrict__ cnt,
                                                    int* __restrict__ partials, int n) {
    __shared__ int sdata[256];
    int t = threadIdx.x;
    int base = blockIdx.x * 1024 + t * 4;
    int s = 0;
#pragma unroll
    for (int j = 0; j < 4; ++j) { int i = base + j; if (i < n) s += cnt[i]; }
    sdata[t] = s;
    __syncthreads();
    for (int off = 128; off > 0; off >>= 1) {
        if (t < off) sdata[t] += sdata[t + off];
        __syncthreads();
    }
    if (t == 0) partials[blockIdx.x] = sdata[0];
}

__global__ void scan2_kernel(int* __restrict__ partials, int nb) {
    if (threadIdx.x == 0 && blockIdx.x == 0) {
        int acc = 0;
        for (int i = 0; i < nb; ++i) { int v = partials[i]; partials[i] = acc; acc += v; }
    }
}

__global__ __launch_bounds__(256) void scan3_kernel(const int* __restrict__ cnt,
                                                    const int* __restrict__ partials,
                                                    int* __restrict__ rowptr,
                                                    int* __restrict__ cursor,
                                                    float* __restrict__ dinv,
                                                    float* __restrict__ selfnorm,
                                                    int n, int E) {
    __shared__ int sdata[256];
    int t = threadIdx.x;
    int base = blockIdx.x * 1024 + t * 4;
    int loc[4];
    int s = 0;
#pragma unroll
    for (int j = 0; j < 4; ++j) {
        int i = base + j;
        loc[j] = (i < n) ? cnt[i] : 0;
        s += loc[j];
    }
    sdata[t] = s;
    __syncthreads();
    if (t == 0) {
        int a = 0;
        for (int i = 0; i < 256; ++i) { int v = sdata[i]; sdata[i] = a; a += v; }
    }
    __syncthreads();
    int run = partials[blockIdx.x] + sdata[t];
#pragma unroll
    for (int j = 0; j < 4; ++j) {
        int i = base + j;
        if (i < n) {
            rowptr[i] = run;
            cursor[i] = run;
            float df = (float)(loc[j] + 1);
            dinv[i] = rsqrtf(df);
            selfnorm[i] = 1.0f / df;
            run += loc[j];
        }
    }
    if (blockIdx.x == 0 && t == 0) rowptr[n] = E;
}

__global__ __launch_bounds__(256) void scatter_kernel(const int* __restrict__ ei,
                                                      int* __restrict__ cursor,
                                                      int* __restrict__ csr, int E) {
    int e = blockIdx.x * 256 + threadIdx.x;
    if (e < E) {
        int pos = atomicAdd(&cursor[ei[E + e]], 1);
        csr[pos] = ei[e];
    }
}

// ---------------- casts ----------------

__global__ __launch_bounds__(256) void cast_bf16_kernel(const float* __restrict__ in,
                                                        unsigned short* __restrict__ out, int n4) {
    int i = blockIdx.x * 256 + threadIdx.x;
    if (i < n4) {
        float4 f = ((const float4*)in)[i];
        ushort4 o;
        o.x = f32_to_bf16(f.x); o.y = f32_to_bf16(f.y);
        o.z = f32_to_bf16(f.z); o.w = f32_to_bf16(f.w);
        ((ushort4*)out)[i] = o;
    }
}

// W[K x M] fp32 -> Wt[M x K] bf16
__global__ __launch_bounds__(256) void cast_transpose_kernel(const float* __restrict__ in,
                                                             unsigned short* __restrict__ out,
                                                             int K, int M) {
    int i = blockIdx.x * 256 + threadIdx.x;
    if (i < K * M) {
        int k = i / M, m2 = i - k * M;
        out[(size_t)m2 * K + k] = f32_to_bf16(in[i]);
    }
}

// ---------------- pre-aggregation: z = A_norm * h + diag(selfnorm) * h ----------------
// LPN lanes per node (W = LPN*8 bf16 feats); each lane owns 8 feats (uint4=16B).
// Edge loop unrolled x4 -> 4 row-gathers + 4 dinv loads in flight per node-group.

__device__ __forceinline__ void acc8(float* acc, uint4 u, float wt) {
    acc[0] += wt * bf16_lo(u.x); acc[1] += wt * bf16_hi(u.x);
    acc[2] += wt * bf16_lo(u.y); acc[3] += wt * bf16_hi(u.y);
    acc[4] += wt * bf16_lo(u.z); acc[5] += wt * bf16_hi(u.z);
    acc[6] += wt * bf16_lo(u.w); acc[7] += wt * bf16_hi(u.w);
}

template <int LPN>
__global__ __launch_bounds__(256) void agg_pre_kernel(const unsigned short* __restrict__ h,
                                                      const int* __restrict__ rowptr,
                                                      const int* __restrict__ csr,
                                                      const float* __restrict__ dinv,
                                                      const float* __restrict__ selfnorm,
                                                      unsigned short* __restrict__ z, int n) {
    const int W = LPN * 8;
    int gtid = blockIdx.x * 256 + threadIdx.x;
    int node = gtid / LPN;
    int sub = gtid % LPN;
    if (node >= n) return;
    int fb = sub * 8;
    const unsigned short* hb = h + fb;
    int beg = rowptr[node], end = rowptr[node + 1];

    float acc[8] = {0.f, 0.f, 0.f, 0.f, 0.f, 0.f, 0.f, 0.f};
    int e = beg;
    for (; e + 4 <= end; e += 4) {
        int s0 = csr[e], s1 = csr[e + 1], s2 = csr[e + 2], s3 = csr[e + 3];
        float w0 = dinv[s0], w1 = dinv[s1], w2 = dinv[s2], w3 = dinv[s3];
        uint4 u0 = *(const uint4*)(hb + (size_t)s0 * W);
        uint4 u1 = *(const uint4*)(hb + (size_t)s1 * W);
        uint4 u2 = *(const uint4*)(hb + (size_t)s2 * W);
        uint4 u3 = *(const uint4*)(hb + (size_t)s3 * W);
        acc8(acc, u0, w0); acc8(acc, u1, w1); acc8(acc, u2, w2); acc8(acc, u3, w3);
    }
    for (; e < end; ++e) {
        int s = csr[e];
        float w = dinv[s];
        uint4 u = *(const uint4*)(hb + (size_t)s * W);
        acc8(acc, u, w);
    }
    float di = dinv[node], sn = selfnorm[node];
    uint4 us = *(const uint4*)(hb + (size_t)node * W);
    float hs[8];
    hs[0] = bf16_lo(us.x); hs[1] = bf16_hi(us.x);
    hs[2] = bf16_lo(us.y); hs[3] = bf16_hi(us.y);
    hs[4] = bf16_lo(us.z); hs[5] = bf16_hi(us.z);
    hs[6] = bf16_lo(us.w); hs[7] = bf16_hi(us.w);
    float o[8];
#pragma unroll
    for (int j = 0; j < 8; ++j) o[j] = acc[j] * di + hs[j] * sn;
    uint4 ov;
    ov.x = ((unsigned int)f32_to_bf16(o[1]) << 16) | f32_to_bf16(o[0]);
    ov.y = ((unsigned int)f32_to_bf16(o[3]) << 16) | f32_to_bf16(o[2]);
    ov.z = ((unsigned int)f32_to_bf16(o[5]) << 16) | f32_to_bf16(o[4]);
    ov.w = ((unsigned int)f32_to_bf16(o[7]) << 16) | f32_to_bf16(o[6]);
    *(uint4*)(z + (size_t)node * W + fb) = ov;
}

// ---------------- bf16 MFMA GEMM + optional fused bias/BN/ReLU epilogue ----------------
// C = A[n,K] @ W[K,M] with Wt given as [M,K]. 64x64 tile, 4 waves 2x2, each wave 2x2
// mfma_f32_16x16x32_bf16. LDS stride 40 shorts: b128-aligned, conflict-free.
// bias!=null: val = (val+bias[c]-m[c])*g[c]*rsqrt(v[c]+eps)+beta[c], relu.
// Cb (bf16, row stride cstride) and/or Cf (fp32, row stride M).

__global__ __launch_bounds__(256) void gemm_bf16_kernel(
    const unsigned short* __restrict__ A, const unsigned short* __restrict__ Wt,
    unsigned short* __restrict__ Cb, int cstride, float* __restrict__ Cf,
    const float* __restrict__ bias, const float* __restrict__ g,
    const float* __restrict__ beta, const float* __restrict__ m,
    const float* __restrict__ v, int nrows, int K, int M) {
    __shared__ short As[64 * 40];
    __shared__ short Bs[64 * 40];
    int tid = threadIdx.x;
    int wave = tid >> 6, lane = tid & 63;
    int quad = lane >> 4, l16 = lane & 15;
    int wr = (wave >> 1) * 32, wc = (wave & 1) * 32;
    int row0 = blockIdx.x * 64, col0 = blockIdx.y * 64;

    int srow = tid >> 2, sseg = tid & 3;

    floatx4 acc[2][2];
#pragma unroll
    for (int i = 0; i < 2; ++i)
#pragma unroll
        for (int j = 0; j < 2; ++j)
#pragma unroll
            for (int r = 0; r < 4; ++r) acc[i][j][r] = 0.f;

    for (int k0 = 0; k0 < K; k0 += 32) {
        uint4 av = make_uint4(0, 0, 0, 0);
        int gr = row0 + srow;
        if (gr < nrows) av = *(const uint4*)(A + (size_t)gr * K + k0 + sseg * 8);
        uint4 bv = make_uint4(0, 0, 0, 0);
        int gc = col0 + srow;
        if (gc < M) bv = *(const uint4*)(Wt + (size_t)gc * K + k0 + sseg * 8);

        *(uint4*)(As + srow * 40 + sseg * 8) = av;
        *(uint4*)(Bs + srow * 40 + sseg * 8) = bv;
        __syncthreads();

        bf16x8 af[2], bfr[2];
#pragma unroll
        for (int i = 0; i < 2; ++i)
            af[i] = *(const bf16x8*)(As + (wr + i * 16 + l16) * 40 + quad * 8);
#pragma unroll
        for (int j = 0; j < 2; ++j)
            bfr[j] = *(const bf16x8*)(Bs + (wc + j * 16 + l16) * 40 + quad * 8);

#pragma unroll
        for (int i = 0; i < 2; ++i)
#pragma unroll
            for (int j = 0; j < 2; ++j)
                acc[i][j] = __builtin_amdgcn_mfma_f32_16x16x32_bf16(af[i], bfr[j], acc[i][j], 0, 0, 0);
        __syncthreads();
    }

    // per-thread cols: col0 + wc + j*16 + l16 (j=0,1) — hoist BN params per j
    float sc[2], sh[2];
#pragma unroll
    for (int j = 0; j < 2; ++j) {
        int col = col0 + wc + j * 16 + l16;
        if (bias && col < M) {
            float s = g[col] * rsqrtf(v[col] + EPSV);
            sc[j] = s;
            sh[j] = (bias[col] - m[col]) * s + beta[col];
        } else {
            sc[j] = 1.f; sh[j] = 0.f;
        }
    }

#pragma unroll
    for (int i = 0; i < 2; ++i) {
#pragma unroll
        for (int r = 0; r < 4; ++r) {
            int row = row0 + wr + i * 16 + quad * 4 + r;
            if (row >= nrows) continue;
#pragma unroll
            for (int j = 0; j < 2; ++j) {
                int col = col0 + wc + j * 16 + l16;
                if (col < M) {
                    float val = acc[i][j][r];
                    if (bias) val = fmaxf(val * sc[j] + sh[j], 0.f);
                    if (Cb) Cb[(size_t)row * cstride + col] = f32_to_bf16(val);
                    if (Cf) Cf[(size_t)row * M + col] = val;
                }
            }
        }
    }
}

// ---------------- layer-3: aggregate h3 (bf16, padded rows of 64) + bias + log_softmax ----
// Wave per node, 4 edge-groups x 16 lanes, lane owns 4 feats (uint2=8B), unroll x2
// -> 8 edges in flight. Cross-group shfl reduction, then 16-lane softmax reductions.

__global__ __launch_bounds__(256) void agg3_lsm_kernel(const unsigned short* __restrict__ h3,
                                                       const int* __restrict__ rowptr,
                                                       const int* __restrict__ csr,
                                                       const float* __restrict__ dinv,
                                                       const float* __restrict__ selfnorm,
                                                       const float* __restrict__ b3,
                                                       float* __restrict__ out, int n) {
    int node = (blockIdx.x * 256 + threadIdx.x) >> 6;
    int lane = threadIdx.x & 63;
    if (node >= n) return;
    int sub = lane & 15, grp = lane >> 4;
    int beg = rowptr[node], end = rowptr[node + 1];
    const unsigned short* hb = h3 + sub * 4;

    float acc[4] = {0.f, 0.f, 0.f, 0.f};
    int e = beg + grp;
    for (; e + 4 < end; e += 8) {
        int s0 = csr[e], s1 = csr[e + 4];
        float w0 = dinv[s0], w1 = dinv[s1];
        uint2 u0 = *(const uint2*)(hb + (size_t)s0 * 64);
        uint2 u1 = *(const uint2*)(hb + (size_t)s1 * 64);
        acc[0] += w0 * bf16_lo(u0.x); acc[1] += w0 * bf16_hi(u0.x);
        acc[2] += w0 * bf16_lo(u0.y); acc[3] += w0 * bf16_hi(u0.y);
        acc[0] += w1 * bf16_lo(u1.x); acc[1] += w1 * bf16_hi(u1.x);
        acc[2] += w1 * bf16_lo(u1.y); acc[3] += w1 * bf16_hi(u1.y);
    }
    for (; e < end; e += 4) {
        int s = csr[e];
        float w = dinv[s];
        uint2 u = *(const uint2*)(hb + (size_t)s * 64);
        acc[0] += w * bf16_lo(u.x); acc[1] += w * bf16_hi(u.x);
        acc[2] += w * bf16_lo(u.y); acc[3] += w * bf16_hi(u.y);
    }
#pragma unroll
    for (int j = 0; j < 4; ++j) {
        acc[j] += __shfl_xor(acc[j], 16, 64);
        acc[j] += __shfl_xor(acc[j], 32, 64);
    }
    float di = dinv[node], sn = selfnorm[node];
    uint2 us = *(const uint2*)(h3 + (size_t)node * 64 + sub * 4);
    float self4[4] = {bf16_lo(us.x), bf16_hi(us.x), bf16_lo(us.y), bf16_hi(us.y)};
    int f0 = sub * 4;
    float z[4];
#pragma unroll
    for (int j = 0; j < 4; ++j) {
        int f = f0 + j;
        int fc = f < 40 ? f : 0;           // clamp to keep b3 read in-bounds
        float val = acc[j] * di + self4[j] * sn + b3[fc];
        z[j] = (f < 40) ? val : -INFINITY;
    }
    float mx = fmaxf(fmaxf(z[0], z[1]), fmaxf(z[2], z[3]));
#pragma unroll
    for (int off = 1; off < 16; off <<= 1) mx = fmaxf(mx, __shfl_xor(mx, off, 64));
    float se = expf(z[0] - mx) + expf(z[1] - mx) + expf(z[2] - mx) + expf(z[3] - mx);
#pragma unroll
    for (int off = 1; off < 16; off <<= 1) se += __shfl_xor(se, off, 64);
    float lse = logf(se);
    if (grp == 0 && sub < 10) {
        float4 o = make_float4(z[0] - mx - lse, z[1] - mx - lse, z[2] - mx - lse, z[3] - mx - lse);
        *(float4*)(out + (size_t)node * 40 + f0) = o;
    }
}

// ---------------- launcher ----------------

extern "C" void kernel_launch(void* const* d_in, const int* in_sizes, int n_in,
                              void* d_out, int out_size, void* d_ws, size_t ws_size,
                              hipStream_t stream) {
    const float* x  = (const float*)d_in[0];
    const int* ei   = (const int*)d_in[1];   // int32
    const float* W1 = (const float*)d_in[2];
    const float* b1 = (const float*)d_in[3];
    const float* g1 = (const float*)d_in[4];
    const float* be1 = (const float*)d_in[5];
    const float* m1 = (const float*)d_in[6];
    const float* v1 = (const float*)d_in[7];
    const float* W2 = (const float*)d_in[8];
    const float* b2 = (const float*)d_in[9];
    const float* g2 = (const float*)d_in[10];
    const float* be2 = (const float*)d_in[11];
    const float* m2 = (const float*)d_in[12];
    const float* v2 = (const float*)d_in[13];
    const float* W3 = (const float*)d_in[14];
    const float* b3 = (const float*)d_in[15];

    const int N = in_sizes[0] / 128;
    const int E = in_sizes[1] / 2;

    float* out_lsm = (float*)d_out;                    // [N,40]
    float* out_emb = (float*)d_out + (size_t)N * 40;   // [N,256]

    char* ws = (char*)d_ws;
    size_t off = 0;
    auto carve = [&](size_t bytes) -> void* {
        void* p = ws + off;
        off = (off + bytes + 255) & ~(size_t)255;
        return p;
    };
    int* cnt      = (int*)carve((size_t)N * 4);
    int* rowptr   = (int*)carve((size_t)(N + 1) * 4);
    int* cursor   = (int*)carve((size_t)N * 4);
    int* partials = (int*)carve(1024);
    int* csr      = (int*)carve((size_t)E * 4);
    float* dinv     = (float*)carve((size_t)N * 4);
    float* selfnorm = (float*)carve((size_t)N * 4);
    unsigned short* W1t = (unsigned short*)carve((size_t)256 * 128 * 2);
    unsigned short* W2t = (unsigned short*)carve((size_t)256 * 256 * 2);
    unsigned short* W3t = (unsigned short*)carve((size_t)40 * 256 * 2);
    // two 256-wide bf16 pools, ping-pong:
    unsigned short* P1 = (unsigned short*)carve((size_t)N * 256 * 2);
    unsigned short* P2 = (unsigned short*)carve((size_t)N * 256 * 2);
    (void)ws_size; (void)n_in; (void)out_size;

    unsigned short* xbf = P1;   // [N,128]
    unsigned short* z1  = P2;   // [N,128]
    unsigned short* y1  = P1;   // [N,256] (xbf dead after agg)
    unsigned short* z2  = P2;   // [N,256] (z1 dead after gemm1)
    unsigned short* y2  = P1;   // [N,256] (y1 dead after agg2)
    unsigned short* h3  = P2;   // [N,64]  (z2 dead after gemm2)

    int nb1k = (N + 1023) / 1024;
    dim3 blk(256);

    // CSR + norms
    hipLaunchKernelGGL(zero_int_kernel, dim3((N + 255) / 256), blk, 0, stream, cnt, N);
    hipLaunchKernelGGL(count_kernel, dim3((E + 255) / 256), blk, 0, stream, ei, cnt, E);
    hipLaunchKernelGGL(scan1_kernel, dim3(nb1k), blk, 0, stream, cnt, partials, N);
    hipLaunchKernelGGL(scan2_kernel, dim3(1), dim3(64), 0, stream, partials, nb1k);
    hipLaunchKernelGGL(scan3_kernel, dim3(nb1k), blk, 0, stream, cnt, partials, rowptr, cursor,
                       dinv, selfnorm, N, E);
    hipLaunchKernelGGL(scatter_kernel, dim3((E + 255) / 256), blk, 0, stream, ei, cursor, csr, E);

    // casts
    int xn4 = N * 128 / 4;
    hipLaunchKernelGGL(cast_bf16_kernel, dim3((xn4 + 255) / 256), blk, 0, stream, x, xbf, xn4);
    hipLaunchKernelGGL(cast_transpose_kernel, dim3((128 * 256 + 255) / 256), blk, 0, stream,
                       W1, W1t, 128, 256);
    hipLaunchKernelGGL(cast_transpose_kernel, dim3((256 * 256 + 255) / 256), blk, 0, stream,
                       W2, W2t, 256, 256);
    hipLaunchKernelGGL(cast_transpose_kernel, dim3((256 * 40 + 255) / 256), blk, 0, stream,
                       W3, W3t, 256, 40);

    dim3 ggrid((N + 63) / 64, 4);
    dim3 ggrid3((N + 63) / 64, 1);

    // layer 1: aggregate x (128-wide) first, then GEMM with fused bias+BN+ReLU
    hipLaunchKernelGGL(HIP_KERNEL_NAME(agg_pre_kernel<16>), dim3((N * 16 + 255) / 256), blk, 0,
                       stream, xbf, rowptr, csr, dinv, selfnorm, z1, N);
    hipLaunchKernelGGL(gemm_bf16_kernel, ggrid, blk, 0, stream, z1, W1t, y1, 256,
                       (float*)nullptr, b1, g1, be1, m1, v1, N, 128, 256);
    // layer 2: aggregate y1 (256-wide), GEMM + BN/ReLU, dual-store bf16 + fp32 out_emb
    hipLaunchKernelGGL(HIP_KERNEL_NAME(agg_pre_kernel<32>), dim3((N * 32 + 255) / 256), blk, 0,
                       stream, y1, rowptr, csr, dinv, selfnorm, z2, N);
    hipLaunchKernelGGL(gemm_bf16_kernel, ggrid, blk, 0, stream, z2, W2t, y2, 256,
                       out_emb, b2, g2, be2, m2, v2, N, 256, 256);
    // layer 3: GEMM first (40-wide out, padded row stride 64), then aggregate + b3 + lsm
    hipLaunchKernelGGL(gemm_bf16_kernel, ggrid3, blk, 0, stream, y2, W3t, h3, 64,
                       (float*)nullptr, (const float*)nullptr, (const float*)nullptr,
                       (const float*)nullptr, (const float*)nullptr, (const float*)nullptr,
                       N, 256, 40);
    hipLaunchKernelGGL(agg3_lsm_kernel, dim3((N + 3) / 4), blk, 0, stream, h3, rowptr, csr,
                       dinv, selfnorm, b3, out_lsm, N);
}